// Round 5
// baseline (702.970 us; speedup 1.0000x reference)
//
#include <hip/hip_runtime.h>
#include <hip/hip_bf16.h>

// Problem constants (fixed in the reference module)
#define N1C  100000
#define N2C  20000
#define DIN_ 128
#define DH_  256
#define DOUT_ 128
#define CAP_LOG2 6                 // 64 slots per destination bucket
#define CAP_     64                // max degree (mean=16, Poisson tail << 64)

// Edge binning (counting-sort pass to make bucket construction L2/LDS-local)
#define BIN_SHIFT 7                // 128 dsts per bin
#define NBIN1 782                  // ceil(100000/128)
#define NBIN2 157                  // ceil(20000/128)
#define NBINS 939
#define CAP_BIN 3072               // mean ~2048 edges/bin, +22 sigma slack
#define CHUNK_A 4096               // edges per bin block

typedef unsigned short ushort_t;
typedef unsigned int   uint_t;
typedef __attribute__((ext_vector_type(8))) short bf16x8;
typedef __attribute__((ext_vector_type(4))) float f32x4;

__device__ __forceinline__ float bf2f(ushort_t u) {
    return __uint_as_float(((uint_t)u) << 16);
}
__device__ __forceinline__ ushort_t f2bf(float f) {
    uint_t x = __float_as_uint(f);
    x += 0x7fffu + ((x >> 16) & 1u);
    return (ushort_t)(x >> 16);
}

// ---------------------------------------------------------------------------
// FAT kernel: blocks [0,nbA) bin edges by dst range; remaining blocks convert
// x and the 4 weight matrices f32->bf16 (independent work, one launch).
// Bin entry packing: (src, dst | bin<<17)  [dst < 2^17, bin < 2^10]
// ---------------------------------------------------------------------------
__global__ __launch_bounds__(256) void convert_and_bin_kernel(
    const float* __restrict__ xsrc, ushort_t* __restrict__ xdst, long long n8,
    const float* __restrict__ w0, const float* __restrict__ w1,
    const float* __restrict__ w2, const float* __restrict__ w3,
    ushort_t* __restrict__ wdst,
    const int* __restrict__ src1, const int* __restrict__ dst1, int E1,
    const int* __restrict__ src2, const int* __restrict__ dst2, int E2,
    int* __restrict__ gTail, uint2* __restrict__ binBuf, int nbA)
{
    __shared__ int hist[NBINS];
    __shared__ int binOff[NBINS];
    __shared__ int runc[NBINS];
    __shared__ int gb[NBINS];
    __shared__ uint2 stage[CHUNK_A];
    __shared__ int wtot[4];

    const int tid = threadIdx.x;

    if ((int)blockIdx.x >= nbA) {
        // ------------------- conversion role -------------------
        const long long t = (long long)((int)blockIdx.x - nbA) * 256 + tid;
        if (t < n8) {
            const float4 v0 = *(const float4*)(xsrc + t * 8);
            const float4 v1 = *(const float4*)(xsrc + t * 8 + 4);
            uint4 o;
            o.x = (uint_t)f2bf(v0.x) | ((uint_t)f2bf(v0.y) << 16);
            o.y = (uint_t)f2bf(v0.z) | ((uint_t)f2bf(v0.w) << 16);
            o.z = (uint_t)f2bf(v1.x) | ((uint_t)f2bf(v1.y) << 16);
            o.w = (uint_t)f2bf(v1.z) | ((uint_t)f2bf(v1.w) << 16);
            *(uint4*)(xdst + t * 8) = o;
        } else {
            const long long t2 = t - n8;           // 0 .. 16383 (64 blocks)
            if (t2 >= 16384) return;
            const int mat = (int)(t2 >> 12);
            const long long idx = (long long)(t2 & 4095) * 8;
            const float* s = (mat == 0) ? w0 : (mat == 1) ? w1 : (mat == 2) ? w2 : w3;
            const float4 v0 = *(const float4*)(s + idx);
            const float4 v1 = *(const float4*)(s + idx + 4);
            uint4 o;
            o.x = (uint_t)f2bf(v0.x) | ((uint_t)f2bf(v0.y) << 16);
            o.y = (uint_t)f2bf(v0.z) | ((uint_t)f2bf(v0.w) << 16);
            o.z = (uint_t)f2bf(v1.x) | ((uint_t)f2bf(v1.y) << 16);
            o.w = (uint_t)f2bf(v1.z) | ((uint_t)f2bf(v1.w) << 16);
            *(uint4*)(wdst + (long long)mat * 32768 + idx) = o;
        }
        return;
    }

    // ------------------- binning role -------------------
    const int tE = E1 + E2;
    const int c0 = blockIdx.x * CHUNK_A;
    const int cend = (c0 + CHUNK_A < tE) ? (c0 + CHUNK_A) : tE;
    const int ccnt = cend - c0;

    for (int b = tid; b < NBINS; b += 256) hist[b] = 0;
    __syncthreads();

    // phase 1: LDS histogram over bins
    for (int i = c0 + tid; i < cend; i += 256) {
        int d, bin;
        if (i < E1) { d = dst1[i];      bin = d >> BIN_SHIFT; }
        else        { d = dst2[i - E1]; bin = NBIN1 + (d >> BIN_SHIFT); }
        atomicAdd(&hist[bin], 1);
    }
    __syncthreads();

    // phase 2: exclusive scan over NBINS + global tail reservation
    {
        int h[4]; int tsum = 0;
        #pragma unroll
        for (int k = 0; k < 4; ++k) {
            const int b = tid * 4 + k;
            h[k] = (b < NBINS) ? hist[b] : 0;
            tsum += h[k];
        }
        int s = tsum;
        #pragma unroll
        for (int o = 1; o < 64; o <<= 1) {
            int t = __shfl_up(s, (unsigned)o);
            if ((tid & 63) >= o) s += t;
        }
        if ((tid & 63) == 63) wtot[tid >> 6] = s;
        __syncthreads();
        int wpre = 0;
        #pragma unroll
        for (int k = 0; k < 4; ++k) wpre += (k < (tid >> 6)) ? wtot[k] : 0;
        int run = wpre + (s - tsum);
        #pragma unroll
        for (int k = 0; k < 4; ++k) {
            const int b = tid * 4 + k;
            if (b < NBINS) {
                binOff[b] = run;
                runc[b]   = run;
                gb[b] = h[k] ? atomicAdd(&gTail[b], h[k]) : 0;
            }
            run += h[k];
        }
    }
    __syncthreads();

    // phase 3: re-read edges, scatter into LDS stage (contiguous per bin)
    for (int i = c0 + tid; i < cend; i += 256) {
        int s, d, bin;
        if (i < E1) { s = src1[i];      d = dst1[i];      bin = d >> BIN_SHIFT; }
        else        { s = src2[i - E1]; d = dst2[i - E1]; bin = NBIN1 + (d >> BIN_SHIFT); }
        const int r = atomicAdd(&runc[bin], 1);
        stage[r] = make_uint2((uint_t)s, (uint_t)d | ((uint_t)bin << 17));
    }
    __syncthreads();

    // phase 4: flush contiguous runs to global per-bin buffers (coalesced)
    for (int i = tid; i < ccnt; i += 256) {
        const uint2 u = stage[i];
        const int bin = (int)(u.y >> 17);
        const int local = gb[bin] + (i - binOff[bin]);
        if (local < CAP_BIN)
            binBuf[(size_t)bin * CAP_BIN + local] = u;
    }
}

// ---------------------------------------------------------------------------
// FUSED layer 1: bucket-build (LDS) + gather-mean (-> LDS A2 tile) + dual
// GEMM + epilogue:  h = relu(BN(l2norm(X@B1^T + agg@B2^T + b2_1)))
// One block per 64 output rows (= half a bin). 256 threads, 60.7 KB LDS
// -> 2 blocks/CU; gather-latency blocks co-schedule with MFMA-busy blocks.
// ---------------------------------------------------------------------------
__global__ __launch_bounds__(256) void gemm1_gather_fused(
    const ushort_t* __restrict__ X, const ushort_t* __restrict__ B1,
    const ushort_t* __restrict__ B2,
    const int* __restrict__ gTail, const uint2* __restrict__ binBuf,
    const float* __restrict__ bias,
    const float* __restrict__ gamma, const float* __restrict__ beta,
    const float* __restrict__ mean, const float* __restrict__ var,
    ushort_t* __restrict__ H, int M)
{
    __shared__ ushort_t As[64][40];        //  5,120 B (phase-0 A staging)
    __shared__ ushort_t Bs[256][40];       // 20,480 B
    __shared__ ushort_t aggLDS[64][136];   // 17,408 B (LDS-resident A2 tile)
    __shared__ int run[64];                //    256 B
    __shared__ int eLDS[64 * CAP_];        // 16,384 B (bucket image)
    __shared__ float rowss[4][64];         //  1,024 B

    const int tid = threadIdx.x;
    const int m0 = blockIdx.x * 64;
    const int bin  = m0 >> BIN_SHIFT;
    const int half = (m0 >> 6) & 1;

    // ---- bucket build from binBuf (LDS atomics only) ----
    if (tid < 64) run[tid] = 0;
    __syncthreads();
    {
        const int t0 = gTail[bin];
        const int nE = (t0 < CAP_BIN) ? t0 : CAP_BIN;
        const uint2* bp = binBuf + (size_t)bin * CAP_BIN;
        for (int i = tid; i < nE; i += 256) {
            const uint2 u = bp[i];
            const int ld = (int)(u.y & 127u);
            if ((ld >> 6) == half) {
                const int l = ld & 63;
                const int slot = atomicAdd(&run[l], 1);
                if (slot < CAP_) eLDS[(l << CAP_LOG2) + slot] = (int)u.x;
            }
        }
    }
    __syncthreads();

    const int wid  = tid >> 6;
    const int lane = tid & 63;

    // ---- gather-mean into aggLDS: wave owns 16 rows, lane owns 2 cols ----
    {
        const int c = lane << 1;
        for (int rr = 0; rr < 16; ++rr) {
            const int l = wid * 16 + rr;
            const int deg = run[l];
            const int end = (deg < CAP_) ? deg : CAP_;
            const int* ep = &eLDS[l << CAP_LOG2];
            float ax = 0.f, ay = 0.f;
            int e = 0;
            for (; e + 3 < end; e += 4) {
                const int s0 = ep[e], s1 = ep[e+1], s2 = ep[e+2], s3 = ep[e+3];
                const uint_t u0 = *(const uint_t*)(X + (size_t)s0 * DIN_ + c);
                const uint_t u1 = *(const uint_t*)(X + (size_t)s1 * DIN_ + c);
                const uint_t u2 = *(const uint_t*)(X + (size_t)s2 * DIN_ + c);
                const uint_t u3 = *(const uint_t*)(X + (size_t)s3 * DIN_ + c);
                ax += bf2f((ushort_t)u0) + bf2f((ushort_t)u1)
                    + bf2f((ushort_t)u2) + bf2f((ushort_t)u3);
                ay += bf2f((ushort_t)(u0 >> 16)) + bf2f((ushort_t)(u1 >> 16))
                    + bf2f((ushort_t)(u2 >> 16)) + bf2f((ushort_t)(u3 >> 16));
            }
            for (; e < end; ++e) {
                const uint_t u0 = *(const uint_t*)(X + (size_t)ep[e] * DIN_ + c);
                ax += bf2f((ushort_t)u0);
                ay += bf2f((ushort_t)(u0 >> 16));
            }
            const float r = 1.0f / fmaxf((float)deg, 1.0f);
            *(uint_t*)&aggLDS[l][c] =
                (uint_t)f2bf(ax * r) | ((uint_t)f2bf(ay * r) << 16);
        }
    }
    __syncthreads();

    // ---- dual GEMM: phase 0 A=X (global), phase 1 A=aggLDS (resident) ----
    const int ar = tid >> 2;
    const int aq = (tid & 3) * 8;
    const bool arow_ok = (m0 + ar) < M;

    const int lm  = lane & 15;
    const int lqq = lane >> 4;
    const int wcol = wid * 64;

    const f32x4 fzero = {0.f, 0.f, 0.f, 0.f};
    f32x4 acc[4][4];
    #pragma unroll
    for (int i = 0; i < 4; ++i)
        #pragma unroll
        for (int j = 0; j < 4; ++j) acc[i][j] = fzero;

    // phase 0: X[m0..m0+64) @ B1^T
    {
        const ushort_t* Ap = X + (size_t)(m0 + ar) * 128 + aq;
        const ushort_t* Bp = B1 + (size_t)tid * 128;
        #pragma unroll
        for (int k0 = 0; k0 < 128; k0 += 32) {
            uint4 a = {0, 0, 0, 0};
            if (arow_ok) a = *(const uint4*)(Ap + k0);
            const uint4 b0 = *(const uint4*)(Bp + k0);
            const uint4 b1 = *(const uint4*)(Bp + k0 + 8);
            const uint4 b2 = *(const uint4*)(Bp + k0 + 16);
            const uint4 b3 = *(const uint4*)(Bp + k0 + 24);

            __syncthreads();
            *(uint4*)&As[ar][aq]   = a;
            *(uint4*)&Bs[tid][0]   = b0;
            *(uint4*)&Bs[tid][8]   = b1;
            *(uint4*)&Bs[tid][16]  = b2;
            *(uint4*)&Bs[tid][24]  = b3;
            __syncthreads();

            bf16x8 af[4], bfr[4];
            #pragma unroll
            for (int i = 0; i < 4; ++i)
                af[i] = *(const bf16x8*)&As[i * 16 + lm][lqq * 8];
            #pragma unroll
            for (int j = 0; j < 4; ++j)
                bfr[j] = *(const bf16x8*)&Bs[wcol + j * 16 + lm][lqq * 8];

            #pragma unroll
            for (int i = 0; i < 4; ++i)
                #pragma unroll
                for (int j = 0; j < 4; ++j)
                    acc[i][j] = __builtin_amdgcn_mfma_f32_16x16x32_bf16(
                        af[i], bfr[j], acc[i][j], 0, 0, 0);
        }
    }

    // phase 1: aggLDS @ B2^T  (A fragments straight from LDS)
    {
        const ushort_t* Bp = B2 + (size_t)tid * 128;
        #pragma unroll
        for (int k0 = 0; k0 < 128; k0 += 32) {
            const uint4 b0 = *(const uint4*)(Bp + k0);
            const uint4 b1 = *(const uint4*)(Bp + k0 + 8);
            const uint4 b2 = *(const uint4*)(Bp + k0 + 16);
            const uint4 b3 = *(const uint4*)(Bp + k0 + 24);

            __syncthreads();
            *(uint4*)&Bs[tid][0]   = b0;
            *(uint4*)&Bs[tid][8]   = b1;
            *(uint4*)&Bs[tid][16]  = b2;
            *(uint4*)&Bs[tid][24]  = b3;
            __syncthreads();

            bf16x8 af[4], bfr[4];
            #pragma unroll
            for (int i = 0; i < 4; ++i)
                af[i] = *(const bf16x8*)&aggLDS[i * 16 + lm][k0 + lqq * 8];
            #pragma unroll
            for (int j = 0; j < 4; ++j)
                bfr[j] = *(const bf16x8*)&Bs[wcol + j * 16 + lm][lqq * 8];

            #pragma unroll
            for (int i = 0; i < 4; ++i)
                #pragma unroll
                for (int j = 0; j < 4; ++j)
                    acc[i][j] = __builtin_amdgcn_mfma_f32_16x16x32_bf16(
                        af[i], bfr[j], acc[i][j], 0, 0, 0);
        }
    }

    // --- fused epilogue: bias -> l2norm -> BN -> relu -> bf16 store ---
    float bj[4], sc[4], sh[4];
    #pragma unroll
    for (int j = 0; j < 4; ++j) {
        const int C = wcol + j * 16 + lm;
        bj[j] = bias[C];
        const float is = rsqrtf(var[C] + 1e-5f);
        sc[j] = gamma[C] * is;
        sh[j] = beta[C] - mean[C] * gamma[C] * is;
    }

    float ss[4][4];
    #pragma unroll
    for (int i = 0; i < 4; ++i) {
        #pragma unroll
        for (int r = 0; r < 4; ++r) {
            float s = 0.f;
            #pragma unroll
            for (int j = 0; j < 4; ++j) {
                const float v = acc[i][j][r] + bj[j];
                acc[i][j][r] = v;
                s += v * v;
            }
            s += __shfl_xor(s, 1);
            s += __shfl_xor(s, 2);
            s += __shfl_xor(s, 4);
            s += __shfl_xor(s, 8);
            ss[i][r] = s;
        }
    }
    if (lm == 0) {
        #pragma unroll
        for (int i = 0; i < 4; ++i)
            #pragma unroll
            for (int r = 0; r < 4; ++r)
                rowss[wid][i * 16 + lqq * 4 + r] = ss[i][r];
    }
    __syncthreads();

    #pragma unroll
    for (int i = 0; i < 4; ++i) {
        #pragma unroll
        for (int r = 0; r < 4; ++r) {
            const int R = i * 16 + lqq * 4 + r;
            const float tot = rowss[0][R] + rowss[1][R] + rowss[2][R] + rowss[3][R];
            const float inv = 1.0f / fmaxf(sqrtf(tot), 1e-12f);
            const int row = m0 + R;
            if (row < M) {
                const size_t base = (size_t)row * DH_ + wcol + lm;
                #pragma unroll
                for (int j = 0; j < 4; ++j) {
                    const float v = fmaxf(acc[i][j][r] * inv * sc[j] + sh[j], 0.f);
                    H[base + j * 16] = f2bf(v);
                }
            }
        }
    }
}

// ---------------------------------------------------------------------------
// Gather 2 (D=256): one block per 64 dsts; bucket image in LDS, then
// gather-mean from h. 512 threads = 8 waves; wave handles 8 rows.
// ---------------------------------------------------------------------------
__global__ __launch_bounds__(512) void gather2_bucket_kernel(
    const ushort_t* __restrict__ X, const int* __restrict__ gTail,
    const uint2* __restrict__ binBuf, ushort_t* __restrict__ agg)
{
    __shared__ int run[64];
    __shared__ int eLDS[64 * CAP_];    // 16 KB

    const int tid = threadIdx.x;
    const int g0 = blockIdx.x << 6;
    const int bin = NBIN1 + (g0 >> BIN_SHIFT);
    const int half = (g0 >> 6) & 1;
    const int t0 = gTail[bin];
    const int nE = (t0 < CAP_BIN) ? t0 : CAP_BIN;

    if (tid < 64) run[tid] = 0;
    __syncthreads();

    const uint2* bp = binBuf + (size_t)bin * CAP_BIN;
    for (int i = tid; i < nE; i += 512) {
        const uint2 u = bp[i];
        const int ld = (int)(u.y & 127u);
        if ((ld >> 6) == half) {
            const int l = ld & 63;
            const int slot = atomicAdd(&run[l], 1);
            if (slot < CAP_) eLDS[(l << CAP_LOG2) + slot] = (int)u.x;
        }
    }
    __syncthreads();

    const int wid = tid >> 6, lane = tid & 63;
    const int c = lane << 2;
    #pragma unroll
    for (int rr = 0; rr < 8; ++rr) {
        const int l = (wid << 3) + rr;
        const int d = g0 + l;
        if (d >= N2C) break;
        const int deg = run[l];
        const int end = (deg < CAP_) ? deg : CAP_;
        const int* ep = &eLDS[l << CAP_LOG2];
        float a0 = 0.f, a1 = 0.f, a2 = 0.f, a3 = 0.f;
        int e = 0;
        for (; e + 3 < end; e += 4) {
            const int s0 = ep[e], s1 = ep[e+1], s2 = ep[e+2], s3 = ep[e+3];
            const uint2 u0 = *(const uint2*)(X + (size_t)s0 * DH_ + c);
            const uint2 u1 = *(const uint2*)(X + (size_t)s1 * DH_ + c);
            const uint2 u2 = *(const uint2*)(X + (size_t)s2 * DH_ + c);
            const uint2 u3 = *(const uint2*)(X + (size_t)s3 * DH_ + c);
            a0 += bf2f((ushort_t)u0.x) + bf2f((ushort_t)u1.x)
                + bf2f((ushort_t)u2.x) + bf2f((ushort_t)u3.x);
            a1 += bf2f((ushort_t)(u0.x >> 16)) + bf2f((ushort_t)(u1.x >> 16))
                + bf2f((ushort_t)(u2.x >> 16)) + bf2f((ushort_t)(u3.x >> 16));
            a2 += bf2f((ushort_t)u0.y) + bf2f((ushort_t)u1.y)
                + bf2f((ushort_t)u2.y) + bf2f((ushort_t)u3.y);
            a3 += bf2f((ushort_t)(u0.y >> 16)) + bf2f((ushort_t)(u1.y >> 16))
                + bf2f((ushort_t)(u2.y >> 16)) + bf2f((ushort_t)(u3.y >> 16));
        }
        for (; e < end; ++e) {
            const uint2 u0 = *(const uint2*)(X + (size_t)ep[e] * DH_ + c);
            a0 += bf2f((ushort_t)u0.x);
            a1 += bf2f((ushort_t)(u0.x >> 16));
            a2 += bf2f((ushort_t)u0.y);
            a3 += bf2f((ushort_t)(u0.y >> 16));
        }
        const float r = 1.0f / fmaxf((float)deg, 1.0f);
        uint2 o;
        o.x = (uint_t)f2bf(a0 * r) | ((uint_t)f2bf(a1 * r) << 16);
        o.y = (uint_t)f2bf(a2 * r) | ((uint_t)f2bf(a3 * r) << 16);
        *(uint2*)(agg + (size_t)d * DH_ + c) = o;
    }
}

// ---------------------------------------------------------------------------
// Fused layer-2 GEMM + epilogue:
//   out = l2norm(A1@B1^T + A2@B2^T + b2_2)    [M x 128] f32, K=256
// ---------------------------------------------------------------------------
__global__ __launch_bounds__(256) void gemm2_fused(
    const ushort_t* __restrict__ A1, const ushort_t* __restrict__ B1,
    const ushort_t* __restrict__ A2, const ushort_t* __restrict__ B2,
    const float* __restrict__ bias,
    float* __restrict__ Cout, int M)
{
    __shared__ ushort_t As[128][40];
    __shared__ ushort_t Bs[128][40];
    __shared__ float rowss[2][128];

    const int tid = threadIdx.x;
    const int m0 = blockIdx.x * 128;

    const int lr = tid >> 1;
    const int lq = (tid & 1) * 8;

    const int wid  = tid >> 6;
    const int lane = tid & 63;
    const int lm   = lane & 15;
    const int lqq  = lane >> 4;
    const int wrow = (wid >> 1) * 64;
    const int wcol = (wid & 1) * 64;
    const int wc   = wid & 1;

    const f32x4 fzero = {0.f, 0.f, 0.f, 0.f};
    f32x4 acc[4][4];
    #pragma unroll
    for (int i = 0; i < 4; ++i)
        #pragma unroll
        for (int j = 0; j < 4; ++j) acc[i][j] = fzero;

    const bool arow_ok = (m0 + lr) < M;

    #pragma unroll
    for (int phase = 0; phase < 2; ++phase) {
        const ushort_t* __restrict__ A = phase ? A2 : A1;
        const ushort_t* __restrict__ B = phase ? B2 : B1;
        const ushort_t* Ap = A + (size_t)(m0 + lr) * 256 + lq;
        const ushort_t* Bp = B + (size_t)lr * 256 + lq;

        for (int k0 = 0; k0 < 256; k0 += 32) {
            uint4 a0 = {0, 0, 0, 0}, a1 = {0, 0, 0, 0};
            if (arow_ok) {
                a0 = *(const uint4*)(Ap + k0);
                a1 = *(const uint4*)(Ap + k0 + 16);
            }
            const uint4 b0 = *(const uint4*)(Bp + k0);
            const uint4 b1 = *(const uint4*)(Bp + k0 + 16);

            __syncthreads();
            *(uint4*)&As[lr][lq]      = a0;
            *(uint4*)&As[lr][lq + 16] = a1;
            *(uint4*)&Bs[lr][lq]      = b0;
            *(uint4*)&Bs[lr][lq + 16] = b1;
            __syncthreads();

            bf16x8 af[4], bfr[4];
            #pragma unroll
            for (int i = 0; i < 4; ++i)
                af[i] = *(const bf16x8*)&As[wrow + i * 16 + lm][lqq * 8];
            #pragma unroll
            for (int j = 0; j < 4; ++j)
                bfr[j] = *(const bf16x8*)&Bs[wcol + j * 16 + lm][lqq * 8];

            #pragma unroll
            for (int i = 0; i < 4; ++i)
                #pragma unroll
                for (int j = 0; j < 4; ++j)
                    acc[i][j] = __builtin_amdgcn_mfma_f32_16x16x32_bf16(
                        af[i], bfr[j], acc[i][j], 0, 0, 0);
        }
    }

    // --- fused epilogue: bias -> l2norm -> f32 store ---
    float bj[4];
    #pragma unroll
    for (int j = 0; j < 4; ++j) bj[j] = bias[wcol + j * 16 + lm];

    float ss[4][4];
    #pragma unroll
    for (int i = 0; i < 4; ++i) {
        #pragma unroll
        for (int r = 0; r < 4; ++r) {
            float s = 0.f;
            #pragma unroll
            for (int j = 0; j < 4; ++j) {
                const float v = acc[i][j][r] + bj[j];
                acc[i][j][r] = v;
                s += v * v;
            }
            s += __shfl_xor(s, 1);
            s += __shfl_xor(s, 2);
            s += __shfl_xor(s, 4);
            s += __shfl_xor(s, 8);
            ss[i][r] = s;
        }
    }
    if (lm == 0) {
        #pragma unroll
        for (int i = 0; i < 4; ++i)
            #pragma unroll
            for (int r = 0; r < 4; ++r)
                rowss[wc][wrow + i * 16 + lqq * 4 + r] = ss[i][r];
    }
    __syncthreads();

    #pragma unroll
    for (int i = 0; i < 4; ++i) {
        #pragma unroll
        for (int r = 0; r < 4; ++r) {
            const int R = wrow + i * 16 + lqq * 4 + r;
            const float tot = rowss[0][R] + rowss[1][R];
            const float inv = 1.0f / fmaxf(sqrtf(tot), 1e-12f);
            const int row = m0 + R;
            if (row < M) {
                const size_t base = (size_t)row * DOUT_ + wcol + lm;
                #pragma unroll
                for (int j = 0; j < 4; ++j)
                    Cout[base + j * 16] = acc[i][j][r] * inv;
            }
        }
    }
}

// ---------------------------------------------------------------------------
extern "C" void kernel_launch(void* const* d_in, const int* in_sizes, int n_in,
                              void* d_out, int out_size, void* d_ws, size_t ws_size,
                              hipStream_t stream)
{
    const float* x     = (const float*)d_in[0];
    const int*   src1  = (const int*)d_in[1];
    const int*   dst1  = (const int*)d_in[2];
    const int*   src2  = (const int*)d_in[3];
    const int*   dst2  = (const int*)d_in[4];
    const float* W1_1  = (const float*)d_in[7];
    const float* W2_1  = (const float*)d_in[8];
    const float* b2_1  = (const float*)d_in[9];
    const float* gamma1= (const float*)d_in[10];
    const float* beta1 = (const float*)d_in[11];
    const float* mean1 = (const float*)d_in[12];
    const float* var1  = (const float*)d_in[13];
    const float* W1_2  = (const float*)d_in[14];
    const float* W2_2  = (const float*)d_in[15];
    const float* b2_2  = (const float*)d_in[16];
    float* out = (float*)d_out;

    const int E1 = in_sizes[1];
    const int E2 = in_sizes[3];
    const int n1 = N1C;
    const int n2 = N2C;

    // Workspace layout (byte offsets), NO aliasing — ws_size ~1.024 GB.
    char* wsb = (char*)d_ws;
    ushort_t* xb     = (ushort_t*)(wsb + 0);            // 128,000,000
    ushort_t* h      = (ushort_t*)(wsb + 128000000);    //  51,200,000
    ushort_t* agg2   = (ushort_t*)(wsb + 204800000);    //  10,240,000
    ushort_t* wb     = (ushort_t*)(wsb + 215040000);    //     262,144
    int*      gTail  = (int*)(wsb + 215302144);         //       3,756 (+pad)
    uint2*    binBuf = (uint2*)(wsb + 215306240);       //  23,076,864 (939*3072*8)
    ushort_t* w11b = wb;
    ushort_t* w21b = wb + 32768;
    ushort_t* w12b = wb + 65536;
    ushort_t* w22b = wb + 98304;

    // --- zero bin tails, then fat kernel: [bin blocks][convert blocks] ---
    hipMemsetAsync(gTail, 0, NBINS * sizeof(int), stream);
    {
        const long long n8 = (long long)500000 * DIN_ / 8;  // 8,000,000
        const int tE = E1 + E2;
        const int nbA = (tE + CHUNK_A - 1) / CHUNK_A;       // ~469 bin blocks
        const int nblk = nbA + (int)(n8 / 256) + 64;        // + convert blocks
        convert_and_bin_kernel<<<nblk, 256, 0, stream>>>(
            x, xb, n8, W1_1, W2_1, W1_2, W2_2, wb,
            src1, dst1, E1, src2, dst2, E2, gTail, binBuf, nbA);
    }

    // --- Layer 1: single fused kernel (bucket + gather + dual GEMM + epi) ---
    gemm1_gather_fused<<<(n1 + 63) / 64, 256, 0, stream>>>(
        xb, w11b, w21b, gTail, binBuf,
        b2_1, gamma1, beta1, mean1, var1, h, n1);

    // --- Layer 2 (bucket-build + gather -> fused GEMM+epilogue) ---
    gather2_bucket_kernel<<<(n2 + 63) / 64, 512, 0, stream>>>(h, gTail, binBuf, agg2);
    gemm2_fused<<<(n2 + 127) / 128, 256, 0, stream>>>(
        h, w12b, agg2, w22b, b2_2, out, n2);
}